// Round 1
// baseline (318.867 us; speedup 1.0000x reference)
//
#include <hip/hip_runtime.h>
#include <math.h>

#define HH 512
#define WW 512
#define BB 4
#define NPIX (BB * HH * WW)

// Constants computed in double (as Python does) then cast to f32.
constexpr float TAUf   = 0.01f;
constexpr float RHOf   = 1.99f;
constexpr float SIGMAf = (float)(1.0 / 0.01 / 72.0);   // 1/tau/72
constexpr float ONE_P_TAU = 1.0f + 0.01f;

// epsilon2_adjoint at (h,w): I0,I1 from u-planes (SoA).
__device__ __forceinline__ void eps2_adj(
    const float* __restrict__ u0, const float* __restrict__ u1,
    const float* __restrict__ u2c, const float* __restrict__ u3,
    int boff, int h, int w, float& i0, float& i1)
{
    int base = boff + h * WW + w;
    float G0  = u0[base];
    float G0d = (h < HH - 1) ? u0[base + WW] : 0.f;
    float G1c = (w >= 1)     ? u1[base]      : 0.f;
    float G1r = (w < WW - 1) ? u1[base + 1]  : 0.f;
    i0 = G0 - G0d - G1r + G1c;
    float G2  = u2c[base];
    float G2r = (w < WW - 1) ? u2c[base + 1] : 0.f;
    float G3  = (h < HH - 1) ? u3[base]      : 0.f;
    float G3u = (h >= 1)     ? u3[base - WW] : 0.f;
    i1 = G2 - G2r - G3 + G3u;
}

__global__ __launch_bounds__(256) void init_kernel(
    const float* __restrict__ y,
    float* __restrict__ x2, float* __restrict__ r20, float* __restrict__ r21,
    float* __restrict__ u0, float* __restrict__ u1,
    float* __restrict__ u2c, float* __restrict__ u3)
{
    int idx = blockIdx.x * 256 + threadIdx.x;
    x2[idx] = y[idx];
    r20[idx] = 0.f; r21[idx] = 0.f;
    u0[idx] = 0.f; u1[idx] = 0.f; u2c[idx] = 0.f; u3[idx] = 0.f;
}

// K1: tmp = tau*eps2_adj(u2); x = (x2 - nabla2_adj(tmp) + tau*y)/(1+tau);
//     r = prox_tau_fr(r2 + tmp); s = 2x - x2; t = 2r - r2;
//     x2 += rho*(x-x2) (written to x2_out); r2 += rho*(r-r2) (in place).
__global__ __launch_bounds__(256) void k1_kernel(
    const float* __restrict__ y, const int* __restrict__ ths_p,
    const float* __restrict__ x2_in, float* __restrict__ x2_out,
    float* __restrict__ r20, float* __restrict__ r21,
    const float* __restrict__ u0, const float* __restrict__ u1,
    const float* __restrict__ u2c, const float* __restrict__ u3,
    float* __restrict__ s, float* __restrict__ t0, float* __restrict__ t1)
{
    int idx = blockIdx.x * 256 + threadIdx.x;
    int w = idx & (WW - 1);
    int h = (idx >> 9) & (HH - 1);
    int b = idx >> 18;
    int boff = b * (HH * WW);

    float lam1 = (float)ths_p[0] * 0.1f;
    float taulam1 = TAUf * lam1;

    // eps2_adjoint at (h,w), (h,w-1), (h-1,w)
    float i0c, i1c;
    eps2_adj(u0, u1, u2c, u3, boff, h, w, i0c, i1c);
    float i0l = 0.f, dum;
    if (w >= 1) eps2_adj(u0, u1, u2c, u3, boff, h, w - 1, i0l, dum);
    float i1u = 0.f;
    if (h >= 1) eps2_adj(u0, u1, u2c, u3, boff, h - 1, w, dum, i1u);

    // nabla2_adjoint(tau * eps2_adj(u2)) at (h,w)
    float na = 0.f;
    if (w < WW - 1) na -= TAUf * i0c;
    if (w >= 1)     na += TAUf * i0l;
    if (h < HH - 1) na -= TAUf * i1c;
    if (h >= 1)     na += TAUf * i1u;

    float x2v = x2_in[idx];
    float x = (x2v - na + TAUf * y[idx]) / ONE_P_TAU;

    // prox_tau_fr(r2 + tmp)
    float r20v = r20[idx], r21v = r21[idx];
    float rr0 = r20v + TAUf * i0c;
    float rr1 = r21v + TAUf * i1c;
    float mag = sqrtf(rr0 * rr0 + rr1 * rr1) / taulam1;
    float den = fmaxf(mag, 1.0f);
    float r0 = rr0 - rr0 / den;
    float r1 = rr1 - rr1 / den;

    s[idx]  = 2.0f * x  - x2v;
    t0[idx] = 2.0f * r0 - r20v;
    t1[idx] = 2.0f * r1 - r21v;

    x2_out[idx] = x2v + RHOf * (x - x2v);
    r20[idx] = r20v + RHOf * (r0 - r20v);
    r21[idx] = r21v + RHOf * (r1 - r21v);
}

// K2: u = prox_sigma_g_conj(u2 + SIGMA * eps2(nabla2(s) - t)); u2 += rho*(u-u2).
__global__ __launch_bounds__(256) void k2_kernel(
    const int* __restrict__ ths_p,
    const float* __restrict__ s, const float* __restrict__ t0, const float* __restrict__ t1,
    float* __restrict__ u0, float* __restrict__ u1,
    float* __restrict__ u2c, float* __restrict__ u3)
{
    int idx = blockIdx.x * 256 + threadIdx.x;
    int w = idx & (WW - 1);
    int h = (idx >> 9) & (HH - 1);
    int b = idx >> 18;
    int boff = b * (HH * WW);

    float lam2 = (float)ths_p[0] * 0.15f;

    // v0(h',w') = (w'<W-1 ? s[h',w'+1]-s[h',w'] : 0) - t0[h',w']
    // v1(h',w') = (h'<H-1 ? s[h'+1,w']-s[h',w'] : 0) - t1[h',w']
    auto v0f = [&](int hh, int ww) -> float {
        int base = boff + hh * WW + ww;
        float d = (ww < WW - 1) ? (s[base + 1] - s[base]) : 0.f;
        return d - t0[base];
    };
    auto v1f = [&](int hh, int ww) -> float {
        int base = boff + hh * WW + ww;
        float d = (hh < HH - 1) ? (s[base + WW] - s[base]) : 0.f;
        return d - t1[base];
    };

    float v0c = v0f(h, w);
    float v1c = v1f(h, w);

    float G0 = v0c - ((h >= 1) ? v0f(h - 1, w) : 0.f);
    float G1 = (w >= 1) ? (v0c - v0f(h, w - 1)) : 0.f;
    float G2 = v1c - ((w >= 1) ? v1f(h, w - 1) : 0.f);
    float G3 = (h < HH - 1) ? (v1f(h + 1, w) - v1c) : 0.f;

    float u0v = u0[idx], u1v = u1[idx], u2v = u2c[idx], u3v = u3[idx];
    float uu0 = u0v + SIGMAf * G0;
    float uu1 = u1v + SIGMAf * G1;
    float uu2 = u2v + SIGMAf * G2;
    float uu3 = u3v + SIGMAf * G3;

    float mag = sqrtf(uu0 * uu0 + uu1 * uu1 + uu2 * uu2 + uu3 * uu3) / lam2;
    float den = fmaxf(mag, 1.0f);
    float n0 = uu0 / den, n1 = uu1 / den, n2 = uu2 / den, n3 = uu3 / den;

    u0[idx] = u0v + RHOf * (n0 - u0v);
    u1[idx] = u1v + RHOf * (n1 - u1v);
    u2c[idx] = u2v + RHOf * (n2 - u2v);
    u3[idx] = u3v + RHOf * (n3 - u3v);
}

extern "C" void kernel_launch(void* const* d_in, const int* in_sizes, int n_in,
                              void* d_out, int out_size, void* d_ws, size_t ws_size,
                              hipStream_t stream)
{
    const float* y   = (const float*)d_in[0];
    const int*   ths = (const int*)d_in[1];
    float* ws = (float*)d_ws;

    float* x2  = ws + 0 * (size_t)NPIX;
    float* r20 = ws + 1 * (size_t)NPIX;
    float* r21 = ws + 2 * (size_t)NPIX;
    float* u0  = ws + 3 * (size_t)NPIX;
    float* u1  = ws + 4 * (size_t)NPIX;
    float* u2c = ws + 5 * (size_t)NPIX;
    float* u3  = ws + 6 * (size_t)NPIX;
    float* s   = ws + 7 * (size_t)NPIX;
    float* t0  = ws + 8 * (size_t)NPIX;
    float* t1  = ws + 9 * (size_t)NPIX;

    dim3 block(256);
    dim3 grid(NPIX / 256);

    init_kernel<<<grid, block, 0, stream>>>(y, x2, r20, r21, u0, u1, u2c, u3);

    for (int it = 0; it < 10; ++it) {
        float* xout = (it == 9) ? (float*)d_out : x2;
        k1_kernel<<<grid, block, 0, stream>>>(y, ths, x2, xout, r20, r21,
                                              u0, u1, u2c, u3, s, t0, t1);
        if (it < 9) {
            k2_kernel<<<grid, block, 0, stream>>>(ths, s, t0, t1, u0, u1, u2c, u3);
        }
    }
}

// Round 2
// 231.173 us; speedup vs baseline: 1.3793x; 1.3793x over previous
//
#include <hip/hip_runtime.h>
#include <math.h>

#define HH 512
#define WW 512
#define BB 4
#define NPIX (BB * HH * WW)

#define T_H 16
#define T_W 64
#define IST 68                 // LDS row stride (floats)
#define I_ROWS (T_H + 4)       // eps2_adj (i0,i1) region rows: h0-2 .. h0+T_H+1
#define S_ROWS (T_H + 3)       // s/t region rows: h0-1 .. h0+T_H+1

constexpr float TAUf   = 0.01f;
constexpr float RHOf   = 1.99f;
constexpr float SIGMAf = (float)(1.0 / 0.01 / 72.0);     // 1/tau/72
constexpr float INV_1P_TAU = (float)(1.0 / 1.01);

// epsilon2_adjoint at (h,w) from SoA u-planes.
__device__ __forceinline__ void eps2_adj(
    const float* __restrict__ u0, const float* __restrict__ u1,
    const float* __restrict__ u2c, const float* __restrict__ u3,
    int boff, int h, int w, float& i0, float& i1)
{
    int base = boff + h * WW + w;
    float G0  = u0[base];
    float G0d = (h < HH - 1) ? u0[base + WW] : 0.f;
    float G1c = (w >= 1)     ? u1[base]      : 0.f;
    float G1r = (w < WW - 1) ? u1[base + 1]  : 0.f;
    i0 = G0 - G0d - G1r + G1c;
    float G2  = u2c[base];
    float G2r = (w < WW - 1) ? u2c[base + 1] : 0.f;
    float G3  = (h < HH - 1) ? u3[base]      : 0.f;
    float G3u = (h >= 1)     ? u3[base - WW] : 0.f;
    i1 = G2 - G2r - G3 + G3u;
}

// One full primal-dual iteration, fused. Block computes:
//  phase 0: i = eps2_adj(u_in) over (T_H+4)x(T_W+3) extended region -> LDS
//  phase 1: x, r, s=2x-x2, t=2r-r2 over (T_H+3)x(T_W+2) region; s,t -> LDS;
//           interior points write x2_out, r2_out
//  phase 2: u_out = prox(u_in + sigma*eps2(nabla2(s)-t)) on 16x64 interior
// FIRST: x2=y, r2=0, u=0 (no init kernel needed). LAST: only x2_out written.
template <bool FIRST, bool LAST>
__global__ __launch_bounds__(256) void fused_iter(
    const float* __restrict__ y, const int* __restrict__ ths_p,
    const float* __restrict__ x2_in, float* __restrict__ x2_out,
    const float* __restrict__ r20_in, const float* __restrict__ r21_in,
    float* __restrict__ r20_out, float* __restrict__ r21_out,
    const float* __restrict__ u0_in, const float* __restrict__ u1_in,
    const float* __restrict__ u2_in, const float* __restrict__ u3_in,
    float* __restrict__ u0_out, float* __restrict__ u1_out,
    float* __restrict__ u2_out, float* __restrict__ u3_out)
{
    __shared__ float i0s[I_ROWS][IST], i1s[I_ROWS][IST];
    __shared__ float ss[S_ROWS][IST], t0s[S_ROWS][IST], t1s[S_ROWS][IST];

    const int tid = threadIdx.x;
    const int w0 = blockIdx.x * T_W;
    const int h0 = blockIdx.y * T_H;
    const int boff = blockIdx.z * (HH * WW);

    const float ths = (float)ths_p[0];
    const float lam1 = ths * 0.1f;
    const float inv_taulam1 = 1.0f / (TAUf * lam1);
    const float lam2 = ths * 0.15f;
    const float inv_lam2 = 1.0f / lam2;

    // ---- phase 0: eps2_adj(u_in) into LDS ----
    if (!FIRST) {
        for (int p = tid; p < I_ROWS * IST; p += 256) {
            int ih = p / IST, iw = p - ih * IST;
            int h = h0 - 2 + ih, w = w0 - 2 + iw;
            float i0 = 0.f, i1 = 0.f;
            if (h >= 0 && h < HH && w >= 0 && w < WW)
                eps2_adj(u0_in, u1_in, u2_in, u3_in, boff, h, w, i0, i1);
            i0s[ih][iw] = i0;
            i1s[ih][iw] = i1;
        }
        __syncthreads();
    }

    // ---- phase 1: x, r, s, t ----
    for (int p = tid; p < S_ROWS * IST; p += 256) {
        int sh = p / IST, sw = p - sh * IST;
        if (sw >= T_W + 2) continue;           // cols w0-1 .. w0+T_W only
        int h = h0 - 1 + sh, w = w0 - 1 + sw;
        float sv = 0.f, t0v = 0.f, t1v = 0.f;
        if (h >= 0 && h < HH && w >= 0 && w < WW) {
            int idx = boff + h * WW + w;
            float i0c = FIRST ? 0.f : i0s[sh + 1][sw + 1];  // i at (h,w)
            float i0l = FIRST ? 0.f : i0s[sh + 1][sw];      // i at (h,w-1)
            float i1c = FIRST ? 0.f : i1s[sh + 1][sw + 1];
            float i1u = FIRST ? 0.f : i1s[sh][sw + 1];      // i at (h-1,w)

            float na = 0.f;                    // nabla2_adjoint(tau * i)
            if (w < WW - 1) na -= TAUf * i0c;
            if (w >= 1)     na += TAUf * i0l;
            if (h < HH - 1) na -= TAUf * i1c;
            if (h >= 1)     na += TAUf * i1u;

            float yv  = y[idx];
            float x2v = FIRST ? yv : x2_in[idx];
            float x = (x2v - na + TAUf * yv) * INV_1P_TAU;

            float r20v = FIRST ? 0.f : r20_in[idx];
            float r21v = FIRST ? 0.f : r21_in[idx];
            float rr0 = r20v + TAUf * i0c;
            float rr1 = r21v + TAUf * i1c;
            float mag = sqrtf(rr0 * rr0 + rr1 * rr1) * inv_taulam1;
            float rinv = 1.0f / fmaxf(mag, 1.0f);
            float r0 = rr0 - rr0 * rinv;
            float r1 = rr1 - rr1 * rinv;

            sv  = 2.0f * x  - x2v;
            t0v = 2.0f * r0 - r20v;
            t1v = 2.0f * r1 - r21v;

            // interior of this block's tile -> relaxation writes
            if (sh >= 1 && sh <= T_H && sw >= 1 && sw <= T_W) {
                x2_out[idx] = x2v + RHOf * (x - x2v);
                if (!LAST) {
                    r20_out[idx] = r20v + RHOf * (r0 - r20v);
                    r21_out[idx] = r21v + RHOf * (r1 - r21v);
                }
            }
        }
        ss[sh][sw]  = sv;
        t0s[sh][sw] = t0v;
        t1s[sh][sw] = t1v;
    }

    if (LAST) return;
    __syncthreads();

    // ---- phase 2: dual update on 16x64 interior ----
    // v0(h',w') = (w'<W-1 ? s(h',w'+1)-s(h',w') : 0) - t0(h',w')
    // v1(h',w') = (h'<H-1 ? s(h'+1,w')-s(h',w') : 0) - t1(h',w')
    // LDS coords: s(h',w') = ss[h'-h0+1][w'-w0+1]
    auto v0f = [&](int sh, int sw, int h, int w) -> float {
        float d = (w < WW - 1) ? (ss[sh][sw + 1] - ss[sh][sw]) : 0.f;
        return d - t0s[sh][sw];
    };
    auto v1f = [&](int sh, int sw, int h, int w) -> float {
        float d = (h < HH - 1) ? (ss[sh + 1][sw] - ss[sh][sw]) : 0.f;
        return d - t1s[sh][sw];
    };

    for (int k = 0; k < 4; ++k) {
        int lh = (tid >> 6) + (k << 2);
        int lw = tid & 63;
        int h = h0 + lh, w = w0 + lw;
        int idx = boff + h * WW + w;
        int sh = lh + 1, sw = lw + 1;

        float v0c = v0f(sh, sw, h, w);
        float v1c = v1f(sh, sw, h, w);

        float G0 = v0c - ((h >= 1) ? v0f(sh - 1, sw, h - 1, w) : 0.f);
        float G1 = (w >= 1) ? (v0c - v0f(sh, sw - 1, h, w - 1)) : 0.f;
        float G2 = v1c - ((w >= 1) ? v1f(sh, sw - 1, h, w - 1) : 0.f);
        float G3 = (h < HH - 1) ? (v1f(sh + 1, sw, h + 1, w) - v1c) : 0.f;

        float u0v, u1v, u2v, u3v;
        if (FIRST) {
            u0v = 0.f; u1v = 0.f; u2v = 0.f; u3v = 0.f;
        } else {
            u0v = u0_in[idx]; u1v = u1_in[idx];
            u2v = u2_in[idx]; u3v = u3_in[idx];
        }
        float uu0 = u0v + SIGMAf * G0;
        float uu1 = u1v + SIGMAf * G1;
        float uu2 = u2v + SIGMAf * G2;
        float uu3 = u3v + SIGMAf * G3;

        float mag = sqrtf(uu0 * uu0 + uu1 * uu1 + uu2 * uu2 + uu3 * uu3) * inv_lam2;
        float uinv = 1.0f / fmaxf(mag, 1.0f);
        float n0 = uu0 * uinv, n1 = uu1 * uinv, n2 = uu2 * uinv, n3 = uu3 * uinv;

        u0_out[idx] = u0v + RHOf * (n0 - u0v);
        u1_out[idx] = u1v + RHOf * (n1 - u1v);
        u2_out[idx] = u2v + RHOf * (n2 - u2v);
        u3_out[idx] = u3v + RHOf * (n3 - u3v);
    }
}

extern "C" void kernel_launch(void* const* d_in, const int* in_sizes, int n_in,
                              void* d_out, int out_size, void* d_ws, size_t ws_size,
                              hipStream_t stream)
{
    const float* y   = (const float*)d_in[0];
    const int*   ths = (const int*)d_in[1];
    float* ws = (float*)d_ws;

    // 7 state planes x 2 (ping-pong): x2, r20, r21, u0, u1, u2, u3
    float* A[7];
    float* B[7];
    for (int i = 0; i < 7; ++i) {
        A[i] = ws + (size_t)i * NPIX;
        B[i] = ws + (size_t)(7 + i) * NPIX;
    }

    float** in  = A;   // iter 0 ignores `in` (FIRST)
    float** out = B;

    dim3 block(256);
    dim3 grid(WW / T_W, HH / T_H, BB);

    for (int it = 0; it < 10; ++it) {
        float* xout = (it == 9) ? (float*)d_out : out[0];
        if (it == 0) {
            fused_iter<true, false><<<grid, block, 0, stream>>>(
                y, ths, in[0], xout, in[1], in[2], out[1], out[2],
                in[3], in[4], in[5], in[6], out[3], out[4], out[5], out[6]);
        } else if (it == 9) {
            fused_iter<false, true><<<grid, block, 0, stream>>>(
                y, ths, in[0], xout, in[1], in[2], out[1], out[2],
                in[3], in[4], in[5], in[6], out[3], out[4], out[5], out[6]);
        } else {
            fused_iter<false, false><<<grid, block, 0, stream>>>(
                y, ths, in[0], xout, in[1], in[2], out[1], out[2],
                in[3], in[4], in[5], in[6], out[3], out[4], out[5], out[6]);
        }
        float** t = in; in = out; out = t;
    }
}